// Round 1
// baseline (56.064 us; speedup 1.0000x reference)
//
#include <hip/hip_runtime.h>

// BP-MLL loss, factorized:
//   sum_{k in Y, l in Ybar} exp(c_l - c_k)
//     = (sum_{l in Ybar} exp(c_l)) * (sum_{k in Y} exp(-c_k))
// so the O(B*L^2) pairwise reference collapses to O(B*L).

#define B_BATCH 32
#define L_LEN   2048

__global__ __launch_bounds__(256) void bpmll_row_kernel(
    const float* __restrict__ c,
    const int*   __restrict__ y,
    float*       __restrict__ row_out)
{
    const int b   = blockIdx.x;
    const int tid = threadIdx.x;
    const float* crow = c + (size_t)b * L_LEN;
    const int*   yrow = y + (size_t)b * L_LEN;

    float s_pos = 0.f;   // sum over y==1 of exp(-c)
    float s_neg = 0.f;   // sum over y!=1 of exp(+c)
    float n_pos = 0.f;   // count of positive labels

    // 2048 elems / 256 threads = 8 per thread = 2 x (float4 + int4)
    #pragma unroll
    for (int base = 0; base < L_LEN; base += 256 * 4) {
        const int i = base + tid * 4;
        const float4 cv = *reinterpret_cast<const float4*>(crow + i);
        const int4   yv = *reinterpret_cast<const int4*>(yrow + i);
        const float cc[4] = {cv.x, cv.y, cv.z, cv.w};
        const int   yy[4] = {yv.x, yv.y, yv.z, yv.w};
        #pragma unroll
        for (int j = 0; j < 4; ++j) {
            const bool pos = (yy[j] == 1);
            const float e = __expf(pos ? -cc[j] : cc[j]);
            if (pos) { s_pos += e; n_pos += 1.f; }
            else     { s_neg += e; }
        }
    }

    // 64-lane wave reduction (wave = 64 on CDNA)
    #pragma unroll
    for (int off = 32; off > 0; off >>= 1) {
        s_pos += __shfl_down(s_pos, off);
        s_neg += __shfl_down(s_neg, off);
        n_pos += __shfl_down(n_pos, off);
    }

    // cross-wave via LDS (4 waves per 256-thread block)
    __shared__ float sm[3][4];
    const int wave = tid >> 6;
    const int lane = tid & 63;
    if (lane == 0) { sm[0][wave] = s_pos; sm[1][wave] = s_neg; sm[2][wave] = n_pos; }
    __syncthreads();

    if (tid == 0) {
        const float sp = sm[0][0] + sm[0][1] + sm[0][2] + sm[0][3];
        const float sn = sm[1][0] + sm[1][1] + sm[1][2] + sm[1][3];
        const float np = sm[2][0] + sm[2][1] + sm[2][2] + sm[2][3];
        const float nn = (float)L_LEN - np;
        row_out[b] = (sp * sn) / (np * nn);
    }
}

__global__ __launch_bounds__(64) void bpmll_final_kernel(
    const float* __restrict__ row_out,
    float*       __restrict__ out)
{
    const int tid = threadIdx.x;
    float v = (tid < B_BATCH) ? row_out[tid] : 0.f;
    #pragma unroll
    for (int off = 32; off > 0; off >>= 1) v += __shfl_down(v, off);
    if (tid == 0) out[0] = v * (1.0f / (float)B_BATCH);
}

extern "C" void kernel_launch(void* const* d_in, const int* in_sizes, int n_in,
                              void* d_out, int out_size, void* d_ws, size_t ws_size,
                              hipStream_t stream)
{
    const float* c = (const float*)d_in[0];
    const int*   y = (const int*)d_in[1];
    float* row = (float*)d_ws;   // 32 floats of scratch (ws is re-poisoned each
                                 // call; we fully overwrite all 32 slots)
    float* out = (float*)d_out;

    bpmll_row_kernel<<<B_BATCH, 256, 0, stream>>>(c, y, row);
    bpmll_final_kernel<<<1, 64, 0, stream>>>(row, out);
}